// Round 2
// baseline (360.698 us; speedup 1.0000x reference)
//
#include <hip/hip_runtime.h>

typedef __bf16 bf16_t;
typedef __bf16 bf16x4 __attribute__((ext_vector_type(4)));
typedef __bf16 bf16x8 __attribute__((ext_vector_type(8)));
typedef short s16x4 __attribute__((ext_vector_type(4)));
typedef float f32x4 __attribute__((ext_vector_type(4)));

#define BN_EPS 1e-3f

#define GLOAD_LDS16(g, l) \
  __builtin_amdgcn_global_load_lds((const __attribute__((address_space(1))) void*)(g), \
                                   (__attribute__((address_space(3))) void*)(l), 16, 0, 0)

// ---------------- fp32 -> bf16 elementwise convert (8 elems/thread) ----------------
__global__ __launch_bounds__(256) void cvt_f32_bf16(
    const float* __restrict__ in, bf16_t* __restrict__ out, long n)
{
  long i = ((long)blockIdx.x * 256 + threadIdx.x) * 8;
  if (i + 8 > n) return;
  f32x4 a = *(const f32x4*)(in + i);
  f32x4 b = *(const f32x4*)(in + i + 4);
  bf16x8 o;
  o[0] = (bf16_t)a[0]; o[1] = (bf16_t)a[1]; o[2] = (bf16_t)a[2]; o[3] = (bf16_t)a[3];
  o[4] = (bf16_t)b[0]; o[5] = (bf16_t)b[1]; o[6] = (bf16_t)b[2]; o[7] = (bf16_t)b[3];
  *(bf16x8*)(out + i) = o;
}

// ---------------- weight transpose fp32 in[R][C] -> bf16 out[C][R] ----------------
__global__ __launch_bounds__(256) void transpose_f32_bf16(
    const float* __restrict__ in, bf16_t* __restrict__ out, int R, int C)
{
  __shared__ bf16_t t[32][33];
  int bx = blockIdx.x * 32, by = blockIdx.y * 32;
  int tx = threadIdx.x, ty = threadIdx.y;
#pragma unroll
  for (int i = 0; i < 32; i += 8)
    t[ty + i][tx] = (bf16_t)in[(long)(by + ty + i) * C + (bx + tx)];
  __syncthreads();
#pragma unroll
  for (int i = 0; i < 32; i += 8)
    out[(long)(bx + ty + i) * R + (by + tx)] = t[tx][ty + i];
}

// ------- Wkv split-transpose: fp32 [256][640] -> WkT[128][256], WvT[512][256] bf16 -------
__global__ __launch_bounds__(256) void wkv_split_transpose(
    const float* __restrict__ in, bf16_t* __restrict__ outK, bf16_t* __restrict__ outV)
{
  __shared__ bf16_t t[32][33];
  int bx = blockIdx.x * 32, by = blockIdx.y * 32;   // bx over 640 cols, by over 256 rows
  int tx = threadIdx.x, ty = threadIdx.y;
#pragma unroll
  for (int i = 0; i < 32; i += 8)
    t[ty + i][tx] = (bf16_t)in[(long)(by + ty + i) * 640 + (bx + tx)];
  __syncthreads();
#pragma unroll
  for (int i = 0; i < 32; i += 8) {
    int c = bx + ty + i;                 // kv channel 0..639
    int h = c / 80, r80 = c - h * 80;
    bf16_t v = t[tx][ty + i];
    if (r80 < 16)
      outK[(long)(h * 16 + r80) * 256 + (by + tx)] = v;
    else
      outV[(long)(h * 64 + (r80 - 16)) * 256 + (by + tx)] = v;
  }
}

// ---------------- fused GEMM + BN (+ scatter epilogues) ----------------
// MODE 0: K   A=xb[32768][256], WkT[128][256] -> K[bh][4096][16]
// MODE 1: Q   A=xb (strided row gather), WqT[128][256] -> Q[bh][1024][16] (*0.25*log2e)
// MODE 2: PROJ A=outp[8192][512], WpT[512][512] -> d_out fp32 [8192][512]
// MODE 3: V^T A=WvT[512][256], B=xb -> Vt[bh*64+dv][4096]  (coalesced Vt writes)
template <int MODE>
__global__ __launch_bounds__(256) void gemm_bn(
    const bf16_t* __restrict__ A, const bf16_t* __restrict__ Wt,
    const float* __restrict__ bias, const float* __restrict__ gamma,
    const float* __restrict__ beta, const float* __restrict__ mean,
    const float* __restrict__ var,
    bf16_t* __restrict__ out0, float* __restrict__ outf)
{
  constexpr int KTOT = (MODE == 2) ? 512 : 256;
  const int lane = threadIdx.x & 63;
  const int w = threadIdx.x >> 6;
  const int quad = lane >> 4, l15 = lane & 15;
  const int m0 = blockIdx.x * 64 + w * 16;
  const int n0 = blockIdx.y * 64;

  int mrow = m0 + l15;
  int arow;
  if constexpr (MODE == 1) {
    int b = mrow >> 10, qp = mrow & 1023;
    arow = (b << 12) + ((qp >> 5) << 7) + ((qp & 31) << 1);
  } else {
    arow = mrow;
  }
  const bf16_t* ap = A + (long)arow * KTOT + quad * 8;
  const bf16_t* bp = Wt + (long)(n0 + l15) * KTOT + quad * 8;

  f32x4 acc[4] = {};
#pragma unroll
  for (int ks = 0; ks < KTOT / 32; ks++) {
    bf16x8 a = *(const bf16x8*)(ap + ks * 32);
#pragma unroll
    for (int nt = 0; nt < 4; nt++) {
      bf16x8 bfr = *(const bf16x8*)(bp + (long)nt * 16 * KTOT + ks * 32);
      acc[nt] = __builtin_amdgcn_mfma_f32_16x16x32_bf16(a, bfr, acc[nt], 0, 0, 0);
    }
  }

  if constexpr (MODE == 3) {
    // rows = V channels, cols = x rows. BN per ROW.
    float sB[4], tB[4], bB[4];
#pragma unroll
    for (int r = 0; r < 4; r++) {
      int ch = m0 + quad * 4 + r;                      // 0..511
      int c = (ch >> 6) * 80 + 16 + (ch & 63);         // kv param index
      sB[r] = gamma[c] / sqrtf(var[c] + BN_EPS);
      tB[r] = beta[c] - mean[c] * sB[r];
      bB[r] = bias[c];
    }
#pragma unroll
    for (int nt = 0; nt < 4; nt++) {
      int n = n0 + nt * 16 + l15;                      // x row
      int b = n >> 12, seq = n & 4095;
#pragma unroll
      for (int r = 0; r < 4; r++) {
        int ch = m0 + quad * 4 + r;
        float y = (acc[nt][r] + bB[r]) * sB[r] + tB[r];
        out0[((long)((b * 8 + (ch >> 6)) * 64 + (ch & 63))) * 4096 + seq] = (bf16_t)y;
      }
    }
    return;
  }

#pragma unroll
  for (int nt = 0; nt < 4; nt++) {
    int col = n0 + nt * 16 + l15;
    int cp;
    if constexpr (MODE == 0) cp = (col >> 4) * 80 + (col & 15);
    else cp = col;
    float s = gamma[cp] / sqrtf(var[cp] + BN_EPS);
    float t = beta[cp] - mean[cp] * s;
    float bia = bias[cp];
#pragma unroll
    for (int r = 0; r < 4; r++) {
      int grow = m0 + quad * 4 + r;
      float y = (acc[nt][r] + bia) * s + t;
      if constexpr (MODE == 0) {
        int h = col >> 4, d = col & 15;
        int b = grow >> 12, seq = grow & 4095;
        out0[((long)((b * 8 + h) * 4096 + seq)) * 16 + d] = (bf16_t)y;   // K [bh][seq][16]
      } else if constexpr (MODE == 1) {
        int h = col >> 4, d = col & 15;
        int b = grow >> 10, qp = grow & 1023;
        out0[((long)((b * 8 + h) * 1024 + qp)) * 16 + d] = (bf16_t)(y * 0.36067376f);
      } else {
        outf[(long)grow * 512 + col] = y;
      }
    }
  }
}

// ---------------- flash attention: 1-wave blocks, 64 q/wave, counted-vmcnt pipeline ----------------
// R2 rework (110 us version was LDS-throughput bound: 20 ds_read_b64 x 512B per wave per
// 64-key tile, x4 waves all reading the same tile = ~13 MB LDS traffic per CU; conflict
// counter 2.94e7 == per-phase model: K 4-way, V 2-way).
// Changes:
//  * 64 q rows per WAVE (4 q-groups of 16), 1 wave per block, grid 1024 = 64bh x 16qb.
//    Same 10 KB tile read now serves 4x the output -> LDS read traffic per work /4.
//  * No barriers (1-wave block). Counted s_waitcnt vmcnt(20): 4 LDS buffers, tiles t+1,t+2
//    DMA in flight while computing tile t (T4). __syncthreads' full vmcnt(0) drain gone.
//  * Conflict-reducing layouts realized through the linear global_load_lds dest (rule 21:
//    choose SOURCE order): K stored [half16B][row] (was [row][32B]: 4-way/phase -> 2-way),
//    V stored [key-octet][dv] (2-way/phase = floor for 16B DMA units + 8B reads).
//  * MFMA dataflow unchanged (verified): S^T = K.Q^T, exp'd C-frag is the PV B-frag,
//    O^T += V^T.P^T; exp2 softmax, scale 0.25*log2e folded into Q.
// Occupancy is 4 waves/CU (LDS 40KB/block; grid avg 4 blocks/CU) - intentional: the
// binding resource is per-CU LDS bandwidth, not wave count.
__global__ __launch_bounds__(64, 1) void attn_kernel(
    const bf16_t* __restrict__ Q, const bf16_t* __restrict__ K,
    const bf16_t* __restrict__ Vt, bf16_t* __restrict__ outp)
{
  const int lane = threadIdx.x;
  const int quad = lane >> 4, l15 = lane & 15;
  const int bh = blockIdx.x & 63, qb = blockIdx.x >> 6;   // qb 0..15
  const int b = bh >> 3, h = bh & 7;
  const bf16_t* Qp = Q + (long)bh * 1024 * 16;
  const char* Kg = (const char*)(K + (long)bh * 4096 * 16);    // [key][16d], 32 B/row
  const char* Vg = (const char*)(Vt + (long)bh * 64 * 4096);   // [dv][4096], 8192 B/row

  // K tile: [half h][row] 16B slots: slot h*64+row = K[key row][d bytes h*16..+15]
  // V tile: [octet ko][dv] 16B slots: slot ko*64+dv = V[dv][keys ko*8..+7]
  __shared__ __align__(16) char Kl[4][2048];
  __shared__ __align__(16) char Vl[4][8192];

  const int q0 = qb * 64;
  // Q^T B-frags: lane(quad,l15) holds Q[q0+g*16+l15][d=quad*4..+3]
  s16x4 qB[4];
#pragma unroll
  for (int g = 0; g < 4; g++)
    qB[g] = *(const s16x4*)(Qp + (long)(q0 + g * 16 + l15) * 16 + quad * 4);

  f32x4 O[4][4] = {};        // [qgroup g][dv tile dt]: lane holds (q=l15, dv=dt*16+quad*4+r)
  float lp[4] = {0.f, 0.f, 0.f, 0.f};
  const f32x4 zf = {0.f, 0.f, 0.f, 0.f};

  const char* ksrc0 = Kg + (long)lane * 32;        // row=lane, half 0
  const char* ksrc1 = ksrc0 + 16;                  // row=lane, half 1
  const char* vsrc  = Vg + (long)lane * 8192;      // dv=lane

  auto stage = [&](int t, int buf) {
    // V: 8 gload_lds16: octet ko -> slots [ko*64 + lane] (lane=dv)
#pragma unroll
    for (int ko = 0; ko < 8; ko++)
      GLOAD_LDS16(vsrc + (long)t * 128 + ko * 16, &Vl[buf][ko * 1024]);
    // K: 2 gload_lds16: halves -> slots [h*64 + lane] (lane=row)
    GLOAD_LDS16(ksrc0 + (long)t * 2048, &Kl[buf][0]);
    GLOAD_LDS16(ksrc1 + (long)t * 2048, &Kl[buf][1024]);
  };

  auto compute = [&](int buf) {
#pragma unroll
    for (int st = 0; st < 4; st++) {
      // kA: lane(quad,l15) = K[st*16+l15][d=quad*4..+3]: half=quad>>1, sub=quad&1
      s16x4 kA = *(const s16x4*)(&Kl[buf][(quad >> 1) * 1024 + (st * 16 + l15) * 16 + (quad & 1) * 8]);
      // vA[dt]: lane = V[dv=dt*16+l15][keys st*16+quad*4..+3]: ko=st*2+(quad>>1), sub=quad&1
      const int vo = (st * 2 + (quad >> 1)) * 1024 + (quad & 1) * 8;
      s16x4 vA[4];
#pragma unroll
      for (int dt = 0; dt < 4; dt++)
        vA[dt] = *(const s16x4*)(&Vl[buf][vo + (dt * 16 + l15) * 16]);
#pragma unroll
      for (int g = 0; g < 4; g++) {
        f32x4 S = __builtin_amdgcn_mfma_f32_16x16x16bf16_1k(kA, qB[g], zf, 0, 0, 0);
        float p0 = __builtin_amdgcn_exp2f(S[0]);
        float p1 = __builtin_amdgcn_exp2f(S[1]);
        float p2 = __builtin_amdgcn_exp2f(S[2]);
        float p3 = __builtin_amdgcn_exp2f(S[3]);
        lp[g] += (p0 + p1) + (p2 + p3);
        bf16x4 pk; pk[0] = (bf16_t)p0; pk[1] = (bf16_t)p1; pk[2] = (bf16_t)p2; pk[3] = (bf16_t)p3;
        s16x4 pB = __builtin_bit_cast(s16x4, pk);
#pragma unroll
        for (int dt = 0; dt < 4; dt++)
          O[g][dt] = __builtin_amdgcn_mfma_f32_16x16x16bf16_1k(vA[dt], pB, O[g][dt], 0, 0, 0);
      }
    }
  };

  stage(0, 0);
  stage(1, 1);
#pragma unroll 4
  for (int t = 0; t < 64; t++) {
    if (t + 2 < 64) {
      stage(t + 2, (t + 2) & 3);
      asm volatile("s_waitcnt vmcnt(20)" ::: "memory");   // tile t's 10 loads done; t+1,t+2 in flight
    } else if (t + 1 < 64) {
      asm volatile("s_waitcnt vmcnt(10)" ::: "memory");
    } else {
      asm volatile("s_waitcnt vmcnt(0)" ::: "memory");
    }
    compute(t & 3);
  }

  // reduce lp over quads: all lanes with same l15 get the full key-sum
#pragma unroll
  for (int g = 0; g < 4; g++) {
    float l = lp[g];
    l += __shfl_xor(l, 16);
    l += __shfl_xor(l, 32);
    float rl = __builtin_amdgcn_rcpf(l);
    int q = q0 + g * 16 + l15;
    long colq = q & 511;
    long rowbase = (long)b * 1024 + (long)h * 128 + (q >> 9);
#pragma unroll
    for (int dt = 0; dt < 4; dt++) {
#pragma unroll
      for (int r = 0; r < 4; r++) {
        int dv = dt * 16 + quad * 4 + r;
        float val = O[g][dt][r] * rl;
        float hs = val * fminf(fmaxf(val + 3.f, 0.f), 6.f) * (1.f / 6.f);
        outp[(rowbase + (long)dv * 2) * 512 + colq] = (bf16_t)hs;
      }
    }
  }
}

extern "C" void kernel_launch(void* const* d_in, const int* in_sizes, int n_in,
                              void* d_out, int out_size, void* d_ws, size_t ws_size,
                              hipStream_t stream)
{
  const float* x    = (const float*)d_in[0];
  const float* Wkv  = (const float*)d_in[1];
  const float* bkv  = (const float*)d_in[2];
  const float* g_kv = (const float*)d_in[3];
  const float* b_kv = (const float*)d_in[4];
  const float* m_kv = (const float*)d_in[5];
  const float* v_kv = (const float*)d_in[6];
  const float* Wq   = (const float*)d_in[7];
  const float* bq   = (const float*)d_in[8];
  const float* g_q  = (const float*)d_in[9];
  const float* b_q  = (const float*)d_in[10];
  const float* m_q  = (const float*)d_in[11];
  const float* v_q  = (const float*)d_in[12];
  const float* Wp   = (const float*)d_in[13];
  const float* bp   = (const float*)d_in[14];
  const float* g_p  = (const float*)d_in[15];
  const float* b_p  = (const float*)d_in[16];
  const float* m_p  = (const float*)d_in[17];
  const float* v_p  = (const float*)d_in[18];

  char* ws = (char*)d_ws;
  bf16_t* xb   = (bf16_t*)ws; ws += (long)8 * 4096 * 256 * 2;
  bf16_t* WkT  = (bf16_t*)ws; ws += (long)128 * 256 * 2;
  bf16_t* WvT  = (bf16_t*)ws; ws += (long)512 * 256 * 2;
  bf16_t* Wq_t = (bf16_t*)ws; ws += (long)128 * 256 * 2;
  bf16_t* Wp_t = (bf16_t*)ws; ws += (long)512 * 512 * 2;
  bf16_t* Qbuf = (bf16_t*)ws; ws += (long)64 * 1024 * 16 * 2;
  bf16_t* Kbuf = (bf16_t*)ws; ws += (long)64 * 4096 * 16 * 2;
  bf16_t* Vtb  = (bf16_t*)ws; ws += (long)64 * 64 * 4096 * 2;
  bf16_t* outp = (bf16_t*)ws; ws += (long)8192 * 512 * 2;
  ws += 16384;  // slack

  cvt_f32_bf16<<<dim3(4096), 256, 0, stream>>>(x, xb, (long)8 * 4096 * 256);

  wkv_split_transpose<<<dim3(20, 8), dim3(32, 8), 0, stream>>>(Wkv, WkT, WvT);
  transpose_f32_bf16<<<dim3(4, 8),   dim3(32, 8), 0, stream>>>(Wq, Wq_t, 256, 128);
  transpose_f32_bf16<<<dim3(16, 16), dim3(32, 8), 0, stream>>>(Wp, Wp_t, 512, 512);

  gemm_bn<0><<<dim3(512, 2), 256, 0, stream>>>(xb, WkT, bkv, g_kv, b_kv, m_kv, v_kv, Kbuf, nullptr);
  gemm_bn<3><<<dim3(8, 512), 256, 0, stream>>>(WvT, xb, bkv, g_kv, b_kv, m_kv, v_kv, Vtb, nullptr);
  gemm_bn<1><<<dim3(128, 2), 256, 0, stream>>>(xb, Wq_t, bq, g_q, b_q, m_q, v_q, Qbuf, nullptr);

  attn_kernel<<<dim3(1024), 64, 0, stream>>>(Qbuf, Kbuf, Vtb, outp);

  gemm_bn<2><<<dim3(128, 8), 256, 0, stream>>>(outp, Wp_t, bp, g_p, b_p, m_p, v_p, nullptr, (float*)d_out);
}

// Round 3
// 348.562 us; speedup vs baseline: 1.0348x; 1.0348x over previous
//
#include <hip/hip_runtime.h>

typedef __bf16 bf16_t;
typedef __bf16 bf16x4 __attribute__((ext_vector_type(4)));
typedef __bf16 bf16x8 __attribute__((ext_vector_type(8)));
typedef short s16x4 __attribute__((ext_vector_type(4)));
typedef float f32x4 __attribute__((ext_vector_type(4)));

#define BN_EPS 1e-3f

#define GLOAD_LDS16(g, l) \
  __builtin_amdgcn_global_load_lds((const __attribute__((address_space(1))) void*)(g), \
                                   (__attribute__((address_space(3))) void*)(l), 16, 0, 0)

// ---------------- fp32 -> bf16 elementwise convert (8 elems/thread) ----------------
__global__ __launch_bounds__(256) void cvt_f32_bf16(
    const float* __restrict__ in, bf16_t* __restrict__ out, long n)
{
  long i = ((long)blockIdx.x * 256 + threadIdx.x) * 8;
  if (i + 8 > n) return;
  f32x4 a = *(const f32x4*)(in + i);
  f32x4 b = *(const f32x4*)(in + i + 4);
  bf16x8 o;
  o[0] = (bf16_t)a[0]; o[1] = (bf16_t)a[1]; o[2] = (bf16_t)a[2]; o[3] = (bf16_t)a[3];
  o[4] = (bf16_t)b[0]; o[5] = (bf16_t)b[1]; o[6] = (bf16_t)b[2]; o[7] = (bf16_t)b[3];
  *(bf16x8*)(out + i) = o;
}

// ---------------- weight transpose fp32 in[R][C] -> bf16 out[C][R] ----------------
__global__ __launch_bounds__(256) void transpose_f32_bf16(
    const float* __restrict__ in, bf16_t* __restrict__ out, int R, int C)
{
  __shared__ bf16_t t[32][33];
  int bx = blockIdx.x * 32, by = blockIdx.y * 32;
  int tx = threadIdx.x, ty = threadIdx.y;
#pragma unroll
  for (int i = 0; i < 32; i += 8)
    t[ty + i][tx] = (bf16_t)in[(long)(by + ty + i) * C + (bx + tx)];
  __syncthreads();
#pragma unroll
  for (int i = 0; i < 32; i += 8)
    out[(long)(bx + ty + i) * R + (by + tx)] = t[tx][ty + i];
}

// ------- Wkv split-transpose: fp32 [256][640] -> WkT[128][256], WvT[512][256] bf16 -------
__global__ __launch_bounds__(256) void wkv_split_transpose(
    const float* __restrict__ in, bf16_t* __restrict__ outK, bf16_t* __restrict__ outV)
{
  __shared__ bf16_t t[32][33];
  int bx = blockIdx.x * 32, by = blockIdx.y * 32;   // bx over 640 cols, by over 256 rows
  int tx = threadIdx.x, ty = threadIdx.y;
#pragma unroll
  for (int i = 0; i < 32; i += 8)
    t[ty + i][tx] = (bf16_t)in[(long)(by + ty + i) * 640 + (bx + tx)];
  __syncthreads();
#pragma unroll
  for (int i = 0; i < 32; i += 8) {
    int c = bx + ty + i;                 // kv channel 0..639
    int h = c / 80, r80 = c - h * 80;
    bf16_t v = t[tx][ty + i];
    if (r80 < 16)
      outK[(long)(h * 16 + r80) * 256 + (by + tx)] = v;
    else
      outV[(long)(h * 64 + (r80 - 16)) * 256 + (by + tx)] = v;
  }
}

// ---------------- fused GEMM + BN (+ scatter epilogues) ----------------
// MODE 0: K   A=xb[32768][256], WkT[128][256] -> K[bh][4096][16]
// MODE 1: Q   A=xb (strided row gather), WqT[128][256] -> Q[bh][1024][16] (*0.25*log2e)
// MODE 2: PROJ A=outp[8192][512], WpT[512][512] -> d_out fp32 [8192][512]
// MODE 3: V^T A=WvT[512][256], B=xb -> Vt[bh*64+dv][4096]  (coalesced Vt writes)
template <int MODE>
__global__ __launch_bounds__(256) void gemm_bn(
    const bf16_t* __restrict__ A, const bf16_t* __restrict__ Wt,
    const float* __restrict__ bias, const float* __restrict__ gamma,
    const float* __restrict__ beta, const float* __restrict__ mean,
    const float* __restrict__ var,
    bf16_t* __restrict__ out0, float* __restrict__ outf)
{
  constexpr int KTOT = (MODE == 2) ? 512 : 256;
  const int lane = threadIdx.x & 63;
  const int w = threadIdx.x >> 6;
  const int quad = lane >> 4, l15 = lane & 15;
  const int m0 = blockIdx.x * 64 + w * 16;
  const int n0 = blockIdx.y * 64;

  int mrow = m0 + l15;
  int arow;
  if constexpr (MODE == 1) {
    int b = mrow >> 10, qp = mrow & 1023;
    arow = (b << 12) + ((qp >> 5) << 7) + ((qp & 31) << 1);
  } else {
    arow = mrow;
  }
  const bf16_t* ap = A + (long)arow * KTOT + quad * 8;
  const bf16_t* bp = Wt + (long)(n0 + l15) * KTOT + quad * 8;

  f32x4 acc[4] = {};
#pragma unroll
  for (int ks = 0; ks < KTOT / 32; ks++) {
    bf16x8 a = *(const bf16x8*)(ap + ks * 32);
#pragma unroll
    for (int nt = 0; nt < 4; nt++) {
      bf16x8 bfr = *(const bf16x8*)(bp + (long)nt * 16 * KTOT + ks * 32);
      acc[nt] = __builtin_amdgcn_mfma_f32_16x16x32_bf16(a, bfr, acc[nt], 0, 0, 0);
    }
  }

  if constexpr (MODE == 3) {
    // rows = V channels, cols = x rows. BN per ROW.
    float sB[4], tB[4], bB[4];
#pragma unroll
    for (int r = 0; r < 4; r++) {
      int ch = m0 + quad * 4 + r;                      // 0..511
      int c = (ch >> 6) * 80 + 16 + (ch & 63);         // kv param index
      sB[r] = gamma[c] / sqrtf(var[c] + BN_EPS);
      tB[r] = beta[c] - mean[c] * sB[r];
      bB[r] = bias[c];
    }
#pragma unroll
    for (int nt = 0; nt < 4; nt++) {
      int n = n0 + nt * 16 + l15;                      // x row
      int b = n >> 12, seq = n & 4095;
#pragma unroll
      for (int r = 0; r < 4; r++) {
        int ch = m0 + quad * 4 + r;
        float y = (acc[nt][r] + bB[r]) * sB[r] + tB[r];
        out0[((long)((b * 8 + (ch >> 6)) * 64 + (ch & 63))) * 4096 + seq] = (bf16_t)y;
      }
    }
    return;
  }

#pragma unroll
  for (int nt = 0; nt < 4; nt++) {
    int col = n0 + nt * 16 + l15;
    int cp;
    if constexpr (MODE == 0) cp = (col >> 4) * 80 + (col & 15);
    else cp = col;
    float s = gamma[cp] / sqrtf(var[cp] + BN_EPS);
    float t = beta[cp] - mean[cp] * s;
    float bia = bias[cp];
#pragma unroll
    for (int r = 0; r < 4; r++) {
      int grow = m0 + quad * 4 + r;
      float y = (acc[nt][r] + bia) * s + t;
      if constexpr (MODE == 0) {
        int h = col >> 4, d = col & 15;
        int b = grow >> 12, seq = grow & 4095;
        out0[((long)((b * 8 + h) * 4096 + seq)) * 16 + d] = (bf16_t)y;   // K [bh][seq][16]
      } else if constexpr (MODE == 1) {
        int h = col >> 4, d = col & 15;
        int b = grow >> 10, qp = grow & 1023;
        out0[((long)((b * 8 + h) * 1024 + qp)) * 16 + d] = (bf16_t)(y * 0.36067376f);
      } else {
        outf[(long)grow * 512 + col] = y;
      }
    }
  }
}

// ---------------- flash attention: 2-wave blocks, 32 q/wave, counted-vmcnt + barrier ----------------
// R3. R2 (1 wave/block, 4 waves/CU = 1/SIMD) proved LDS bw was NOT binding (conflicts /5.6,
// traffic /4, time flat): with 1 wave/SIMD the VALU softmax (44% = 49 us/CU) and MFMA (31% =
// 35 us/CU) SERIALIZE inside each wave. Fix:
//  * 2 waves/block share the staged K/V tiles, 32 q rows each; grid 1024 -> 4 blocks x 2
//    waves = 8 waves/CU = 2/SIMD: one wave's softmax VALU overlaps the other's MFMA (m114).
//  * Sync: each wave stages 5 of the 10 tile loads; counted s_waitcnt vmcnt(10) (own t+1,t+2
//    in flight) then raw s_barrier (+sched_barrier pin) - never a vmcnt(0) drain in-loop.
//  * lp now accumulated ON THE MFMA PIPE: lpacc = mfma(ones, pB, lpacc) sums P over keys
//    (every C row = column sum); deletes 3 serial VALU adds/iter + the epilogue shuffles,
//    and normalizes by the sum of the bf16-rounded P actually used in PV.
// Layouts (conflict-clean, rule 21: linear gload_lds dest, source order chosen):
//   K tile [half][row] 16B slots; V tile [octet][dv] 16B slots. Math unchanged (verified):
//   S^T = K.Q^T, exp'd C-frag IS the PV B-frag, O^T += V^T.P^T, exp2 with scale in Q.
__global__ __launch_bounds__(128, 2) void attn_kernel(
    const bf16_t* __restrict__ Q, const bf16_t* __restrict__ K,
    const bf16_t* __restrict__ Vt, bf16_t* __restrict__ outp)
{
  const int tid = threadIdx.x;
  const int lane = tid & 63, w = tid >> 6;                // 2 waves
  const int quad = lane >> 4, l15 = lane & 15;
  const int bh = blockIdx.x & 63, qb = blockIdx.x >> 6;   // qb 0..15
  const int b = bh >> 3, h = bh & 7;
  const bf16_t* Qp = Q + (long)bh * 1024 * 16;
  const char* Kg = (const char*)(K + (long)bh * 4096 * 16);    // [key][16d], 32 B/row
  const char* Vg = (const char*)(Vt + (long)bh * 64 * 4096);   // [dv][4096], 8192 B/row

  // K tile: [half h][row] 16B slots: slot h*64+row = K[key row][d bytes h*16..+15]
  // V tile: [octet ko][dv] 16B slots: slot ko*64+dv = V[dv][keys ko*8..+7]
  __shared__ __align__(16) char Kl[4][2048];
  __shared__ __align__(16) char Vl[4][8192];

  const int q0 = qb * 64 + w * 32;
  // Q^T B-frags: lane(quad,l15) holds Q[q0+g*16+l15][d=quad*4..+3]
  s16x4 qB[2];
#pragma unroll
  for (int g = 0; g < 2; g++)
    qB[g] = *(const s16x4*)(Qp + (long)(q0 + g * 16 + l15) * 16 + quad * 4);

  f32x4 O[2][4] = {};        // [qgroup g][dv tile dt]: lane holds (q=l15, dv=dt*16+quad*4+r)
  f32x4 lpacc[2] = {};       // ones-MFMA accumulator: every row = sum_k P[k][q=l15]
  const f32x4 zf = {0.f, 0.f, 0.f, 0.f};

  bf16x4 onesb; onesb[0] = (bf16_t)1.f; onesb[1] = (bf16_t)1.f;
  onesb[2] = (bf16_t)1.f; onesb[3] = (bf16_t)1.f;
  const s16x4 onesA = __builtin_bit_cast(s16x4, onesb);

  // staging split: wave w stages V octets w*4..w*4+3 and K half w (5 loads/wave/tile)
  const char* vsrc = Vg + (long)lane * 8192 + w * 64;     // lane=dv, + (w*4 octets)*16B
  const char* ksrc = Kg + (long)lane * 32 + w * 16;       // lane=row, half w

  auto stage = [&](int t, int buf) {
#pragma unroll
    for (int ko = 0; ko < 4; ko++)
      GLOAD_LDS16(vsrc + (long)t * 128 + ko * 16, &Vl[buf][(w * 4 + ko) * 1024]);
    GLOAD_LDS16(ksrc + (long)t * 2048, &Kl[buf][w * 1024]);
  };

  auto compute = [&](int buf) {
#pragma unroll
    for (int st = 0; st < 4; st++) {
      // kA: lane(quad,l15) = K[st*16+l15][d=quad*4..+3]: half=quad>>1, sub=quad&1
      s16x4 kA = *(const s16x4*)(&Kl[buf][(quad >> 1) * 1024 + (st * 16 + l15) * 16 + (quad & 1) * 8]);
      // vA[dt]: lane = V[dv=dt*16+l15][keys st*16+quad*4..+3]: ko=st*2+(quad>>1), sub=quad&1
      const int vo = (st * 2 + (quad >> 1)) * 1024 + (quad & 1) * 8;
      s16x4 vA[4];
#pragma unroll
      for (int dt = 0; dt < 4; dt++)
        vA[dt] = *(const s16x4*)(&Vl[buf][vo + (dt * 16 + l15) * 16]);
#pragma unroll
      for (int g = 0; g < 2; g++) {
        f32x4 S = __builtin_amdgcn_mfma_f32_16x16x16bf16_1k(kA, qB[g], zf, 0, 0, 0);
        float p0 = __builtin_amdgcn_exp2f(S[0]);
        float p1 = __builtin_amdgcn_exp2f(S[1]);
        float p2 = __builtin_amdgcn_exp2f(S[2]);
        float p3 = __builtin_amdgcn_exp2f(S[3]);
        bf16x4 pk; pk[0] = (bf16_t)p0; pk[1] = (bf16_t)p1; pk[2] = (bf16_t)p2; pk[3] = (bf16_t)p3;
        s16x4 pB = __builtin_bit_cast(s16x4, pk);
        lpacc[g] = __builtin_amdgcn_mfma_f32_16x16x16bf16_1k(onesA, pB, lpacc[g], 0, 0, 0);
#pragma unroll
        for (int dt = 0; dt < 4; dt++)
          O[g][dt] = __builtin_amdgcn_mfma_f32_16x16x16bf16_1k(vA[dt], pB, O[g][dt], 0, 0, 0);
      }
    }
  };

  stage(0, 0);
  stage(1, 1);
#pragma unroll 4
  for (int t = 0; t < 64; t++) {
    if (t + 2 < 64) {
      stage(t + 2, (t + 2) & 3);
      asm volatile("s_waitcnt vmcnt(10)" ::: "memory");   // own tile-t loads done; t+1,t+2 in flight
    } else if (t + 1 < 64) {
      asm volatile("s_waitcnt vmcnt(5)" ::: "memory");
    } else {
      asm volatile("s_waitcnt vmcnt(0)" ::: "memory");
    }
    __builtin_amdgcn_s_barrier();        // partner wave's tile-t loads also done (it waited too)
    __builtin_amdgcn_sched_barrier(0);   // pin: no ds_read hoisted above the barrier (rule 18)
    compute(t & 3);
  }

  // lpacc rows all equal the key-sum for q=l15: no cross-lane reduce needed
#pragma unroll
  for (int g = 0; g < 2; g++) {
    float rl = __builtin_amdgcn_rcpf(lpacc[g][0]);
    int q = q0 + g * 16 + l15;
    long colq = q & 511;
    long rowbase = (long)b * 1024 + (long)h * 128 + (q >> 9);
#pragma unroll
    for (int dt = 0; dt < 4; dt++) {
#pragma unroll
      for (int r = 0; r < 4; r++) {
        int dv = dt * 16 + quad * 4 + r;
        float val = O[g][dt][r] * rl;
        float hs = val * fminf(fmaxf(val + 3.f, 0.f), 6.f) * (1.f / 6.f);
        outp[(rowbase + (long)dv * 2) * 512 + colq] = (bf16_t)hs;
      }
    }
  }
}

extern "C" void kernel_launch(void* const* d_in, const int* in_sizes, int n_in,
                              void* d_out, int out_size, void* d_ws, size_t ws_size,
                              hipStream_t stream)
{
  const float* x    = (const float*)d_in[0];
  const float* Wkv  = (const float*)d_in[1];
  const float* bkv  = (const float*)d_in[2];
  const float* g_kv = (const float*)d_in[3];
  const float* b_kv = (const float*)d_in[4];
  const float* m_kv = (const float*)d_in[5];
  const float* v_kv = (const float*)d_in[6];
  const float* Wq   = (const float*)d_in[7];
  const float* bq   = (const float*)d_in[8];
  const float* g_q  = (const float*)d_in[9];
  const float* b_q  = (const float*)d_in[10];
  const float* m_q  = (const float*)d_in[11];
  const float* v_q  = (const float*)d_in[12];
  const float* Wp   = (const float*)d_in[13];
  const float* bp   = (const float*)d_in[14];
  const float* g_p  = (const float*)d_in[15];
  const float* b_p  = (const float*)d_in[16];
  const float* m_p  = (const float*)d_in[17];
  const float* v_p  = (const float*)d_in[18];

  char* ws = (char*)d_ws;
  bf16_t* xb   = (bf16_t*)ws; ws += (long)8 * 4096 * 256 * 2;
  bf16_t* WkT  = (bf16_t*)ws; ws += (long)128 * 256 * 2;
  bf16_t* WvT  = (bf16_t*)ws; ws += (long)512 * 256 * 2;
  bf16_t* Wq_t = (bf16_t*)ws; ws += (long)128 * 256 * 2;
  bf16_t* Wp_t = (bf16_t*)ws; ws += (long)512 * 512 * 2;
  bf16_t* Qbuf = (bf16_t*)ws; ws += (long)64 * 1024 * 16 * 2;
  bf16_t* Kbuf = (bf16_t*)ws; ws += (long)64 * 4096 * 16 * 2;
  bf16_t* Vtb  = (bf16_t*)ws; ws += (long)64 * 64 * 4096 * 2;
  bf16_t* outp = (bf16_t*)ws; ws += (long)8192 * 512 * 2;
  ws += 16384;  // slack

  cvt_f32_bf16<<<dim3(4096), 256, 0, stream>>>(x, xb, (long)8 * 4096 * 256);

  wkv_split_transpose<<<dim3(20, 8), dim3(32, 8), 0, stream>>>(Wkv, WkT, WvT);
  transpose_f32_bf16<<<dim3(4, 8),   dim3(32, 8), 0, stream>>>(Wq, Wq_t, 256, 128);
  transpose_f32_bf16<<<dim3(16, 16), dim3(32, 8), 0, stream>>>(Wp, Wp_t, 512, 512);

  gemm_bn<0><<<dim3(512, 2), 256, 0, stream>>>(xb, WkT, bkv, g_kv, b_kv, m_kv, v_kv, Kbuf, nullptr);
  gemm_bn<3><<<dim3(8, 512), 256, 0, stream>>>(WvT, xb, bkv, g_kv, b_kv, m_kv, v_kv, Vtb, nullptr);
  gemm_bn<1><<<dim3(128, 2), 256, 0, stream>>>(xb, Wq_t, bq, g_q, b_q, m_q, v_q, Qbuf, nullptr);

  attn_kernel<<<dim3(1024), 128, 0, stream>>>(Qbuf, Kbuf, Vtb, outp);

  gemm_bn<2><<<dim3(128, 8), 256, 0, stream>>>(outp, Wp_t, bp, g_p, b_p, m_p, v_p, nullptr, (float*)d_out);
}

// Round 4
// 322.923 us; speedup vs baseline: 1.1170x; 1.0794x over previous
//
#include <hip/hip_runtime.h>

typedef __bf16 bf16_t;
typedef __bf16 bf16x4 __attribute__((ext_vector_type(4)));
typedef __bf16 bf16x8 __attribute__((ext_vector_type(8)));
typedef short s16x4 __attribute__((ext_vector_type(4)));
typedef float f32x4 __attribute__((ext_vector_type(4)));

#define BN_EPS 1e-3f

#define GLOAD_LDS16(g, l) \
  __builtin_amdgcn_global_load_lds((const __attribute__((address_space(1))) void*)(g), \
                                   (__attribute__((address_space(3))) void*)(l), 16, 0, 0)

// ---------------- fp32 -> bf16 elementwise convert (8 elems/thread) ----------------
__global__ __launch_bounds__(256) void cvt_f32_bf16(
    const float* __restrict__ in, bf16_t* __restrict__ out, long n)
{
  long i = ((long)blockIdx.x * 256 + threadIdx.x) * 8;
  if (i + 8 > n) return;
  f32x4 a = *(const f32x4*)(in + i);
  f32x4 b = *(const f32x4*)(in + i + 4);
  bf16x8 o;
  o[0] = (bf16_t)a[0]; o[1] = (bf16_t)a[1]; o[2] = (bf16_t)a[2]; o[3] = (bf16_t)a[3];
  o[4] = (bf16_t)b[0]; o[5] = (bf16_t)b[1]; o[6] = (bf16_t)b[2]; o[7] = (bf16_t)b[3];
  *(bf16x8*)(out + i) = o;
}

// ---------------- weight transpose fp32 in[R][C] -> bf16 out[C][R] ----------------
__global__ __launch_bounds__(256) void transpose_f32_bf16(
    const float* __restrict__ in, bf16_t* __restrict__ out, int R, int C)
{
  __shared__ bf16_t t[32][33];
  int bx = blockIdx.x * 32, by = blockIdx.y * 32;
  int tx = threadIdx.x, ty = threadIdx.y;
#pragma unroll
  for (int i = 0; i < 32; i += 8)
    t[ty + i][tx] = (bf16_t)in[(long)(by + ty + i) * C + (bx + tx)];
  __syncthreads();
#pragma unroll
  for (int i = 0; i < 32; i += 8)
    out[(long)(bx + ty + i) * R + (by + tx)] = t[tx][ty + i];
}

// ------- Wkv split-transpose: fp32 [256][640] -> WkT[128][256], WvT[512][256] bf16 -------
__global__ __launch_bounds__(256) void wkv_split_transpose(
    const float* __restrict__ in, bf16_t* __restrict__ outK, bf16_t* __restrict__ outV)
{
  __shared__ bf16_t t[32][33];
  int bx = blockIdx.x * 32, by = blockIdx.y * 32;   // bx over 640 cols, by over 256 rows
  int tx = threadIdx.x, ty = threadIdx.y;
#pragma unroll
  for (int i = 0; i < 32; i += 8)
    t[ty + i][tx] = (bf16_t)in[(long)(by + ty + i) * 640 + (bx + tx)];
  __syncthreads();
#pragma unroll
  for (int i = 0; i < 32; i += 8) {
    int c = bx + ty + i;                 // kv channel 0..639
    int h = c / 80, r80 = c - h * 80;
    bf16_t v = t[tx][ty + i];
    if (r80 < 16)
      outK[(long)(h * 16 + r80) * 256 + (by + tx)] = v;
    else
      outV[(long)(h * 64 + (r80 - 16)) * 256 + (by + tx)] = v;
  }
}

// ---------------- fused GEMM + BN (+ scatter epilogues) ----------------
// MODE 0: K   A=xb[32768][256], WkT[128][256] -> K[bh][4096][16]
// MODE 1: Q   A=xb (strided row gather), WqT[128][256] -> Q[bh][1024][16] (*0.25*log2e)
// MODE 2: PROJ A=outp[8192][512], WpT[512][512] -> d_out fp32 [8192][512]
// MODE 3: V^T A=WvT[512][256], B=xb -> Vt2 interleaved for attn's x32 PV MFMA:
//   elem (bh, key, dv) -> idx = bh<<18 | kb<<11 | qd<<9 | dv<<3 | j
//   where kb=key>>5, s32=key&31, qd=(s32&15)>>2, j=(s32>>4)*4+(s32&3)
//   (16B unit (bh,kb,qd,dv) holds keys {kb*32+qd*4+0..3, kb*32+16+qd*4+0..3} = the
//    slot->key map of the attn P B-frag, so PV contracts slot-by-slot correctly)
template <int MODE>
__global__ __launch_bounds__(256) void gemm_bn(
    const bf16_t* __restrict__ A, const bf16_t* __restrict__ Wt,
    const float* __restrict__ bias, const float* __restrict__ gamma,
    const float* __restrict__ beta, const float* __restrict__ mean,
    const float* __restrict__ var,
    bf16_t* __restrict__ out0, float* __restrict__ outf)
{
  constexpr int KTOT = (MODE == 2) ? 512 : 256;
  const int lane = threadIdx.x & 63;
  const int w = threadIdx.x >> 6;
  const int quad = lane >> 4, l15 = lane & 15;
  const int m0 = blockIdx.x * 64 + w * 16;
  const int n0 = blockIdx.y * 64;

  int mrow = m0 + l15;
  int arow;
  if constexpr (MODE == 1) {
    int b = mrow >> 10, qp = mrow & 1023;
    arow = (b << 12) + ((qp >> 5) << 7) + ((qp & 31) << 1);
  } else {
    arow = mrow;
  }
  const bf16_t* ap = A + (long)arow * KTOT + quad * 8;
  const bf16_t* bp = Wt + (long)(n0 + l15) * KTOT + quad * 8;

  f32x4 acc[4] = {};
#pragma unroll
  for (int ks = 0; ks < KTOT / 32; ks++) {
    bf16x8 a = *(const bf16x8*)(ap + ks * 32);
#pragma unroll
    for (int nt = 0; nt < 4; nt++) {
      bf16x8 bfr = *(const bf16x8*)(bp + (long)nt * 16 * KTOT + ks * 32);
      acc[nt] = __builtin_amdgcn_mfma_f32_16x16x32_bf16(a, bfr, acc[nt], 0, 0, 0);
    }
  }

  if constexpr (MODE == 3) {
    // rows = V channels, cols = x rows. BN per ROW.
    float sB[4], tB[4], bB[4];
#pragma unroll
    for (int r = 0; r < 4; r++) {
      int ch = m0 + quad * 4 + r;                      // 0..511
      int c = (ch >> 6) * 80 + 16 + (ch & 63);         // kv param index
      sB[r] = gamma[c] / sqrtf(var[c] + BN_EPS);
      tB[r] = beta[c] - mean[c] * sB[r];
      bB[r] = bias[c];
    }
#pragma unroll
    for (int nt = 0; nt < 4; nt++) {
      int n = n0 + nt * 16 + l15;                      // x row
      int b = n >> 12, seq = n & 4095;
      int kb = seq >> 5, s32 = seq & 31;
      int qd = (s32 & 15) >> 2, j = (s32 >> 4) * 4 + (s32 & 3);
#pragma unroll
      for (int r = 0; r < 4; r++) {
        int ch = m0 + quad * 4 + r;
        float y = (acc[nt][r] + bB[r]) * sB[r] + tB[r];
        int h2 = ch >> 6, dv = ch & 63;
        out0[(((long)(b * 8 + h2)) << 18) + (kb << 11) + (qd << 9) + (dv << 3) + j] = (bf16_t)y;
      }
    }
    return;
  }

#pragma unroll
  for (int nt = 0; nt < 4; nt++) {
    int col = n0 + nt * 16 + l15;
    int cp;
    if constexpr (MODE == 0) cp = (col >> 4) * 80 + (col & 15);
    else cp = col;
    float s = gamma[cp] / sqrtf(var[cp] + BN_EPS);
    float t = beta[cp] - mean[cp] * s;
    float bia = bias[cp];
#pragma unroll
    for (int r = 0; r < 4; r++) {
      int grow = m0 + quad * 4 + r;
      float y = (acc[nt][r] + bia) * s + t;
      if constexpr (MODE == 0) {
        int h = col >> 4, d = col & 15;
        int b = grow >> 12, seq = grow & 4095;
        out0[((long)((b * 8 + h) * 4096 + seq)) * 16 + d] = (bf16_t)y;   // K [bh][seq][16]
      } else if constexpr (MODE == 1) {
        int h = col >> 4, d = col & 15;
        int b = grow >> 10, qp = grow & 1023;
        out0[((long)((b * 8 + h) * 1024 + qp)) * 16 + d] = (bf16_t)(y * 0.36067376f);
      } else {
        outf[(long)grow * 512 + col] = y;
      }
    }
  }
}

// ---------------- flash attention: all-x32 MFMA, 4-wave blocks, depth-2 counted vmcnt ----------------
// R4. Counter archaeology (R0/R1/R3): busy_cyc/instr = 16.8 cyc for mfma_16x16x16bf16_1k in
// all three rounds -- the CDNA3-compat K=16 op is ~3.5x slower than the native 16x16x32
// (4.85 cyc, 2x FLOP). MFMA demand was 103k cyc/SIMD = 43 us, the floor R3 sat on.
// Changes:
//  * QK^T via mfma_f32_16x16x32_bf16: d=16 zero-padded to K=32 (quads 2,3: qB=0; kA aliases
//    the real halves -- 0 x finite = 0). C-layout of x32 == verified 16x16 mapping, so all
//    downstream P handling is unchanged. 4 MFMA/tile64 vs 16.
//  * PV via x32 contracting 32 keys/MFMA: V is written by gemm<3> in the exact (kb,quad,dv,j)
//    interleave matching P's natural slot->key map (slot pairing is all the HW needs). 8 vs 32.
//  * lp (ones-row trick) via x32: k-slot sum is permutation invariant. 2 vs 8.
//  * 4-wave blocks (16 q/wave), 40 KB LDS (4 bufs x 10KB), grid 1024 -> 4 blocks/CU =
//    4 waves/SIMD (2x R3). Depth-2 pipeline: stage(t+2) AFTER the barrier (race-safe: all
//    waves past barrier t read only buf t&3; (t+2)&3 != t&3), counted vmcnt (w<2: 2, else 3).
//  * All ds_reads 16B phase-consecutive -> conflict-free; V staging source fully contiguous.
__global__ __launch_bounds__(256, 4) void attn_kernel(
    const bf16_t* __restrict__ Q, const bf16_t* __restrict__ K,
    const bf16_t* __restrict__ Vt, bf16_t* __restrict__ outp)
{
  const int tid = threadIdx.x;
  const int lane = tid & 63, w = tid >> 6;                // 4 waves
  const int quad = lane >> 4, l15 = lane & 15;
  const int bh = blockIdx.x & 63, qb = blockIdx.x >> 6;   // qb 0..15
  const int b = bh >> 3, h = bh & 7;
  const bf16_t* Qp = Q + (long)bh * 1024 * 16;
  const char* Kg = (const char*)(K + (long)bh * 4096 * 16);     // [key][16d], 32 B/row
  const char* Vg = (const char*)(Vt + ((long)bh << 18));        // interleaved, 512 KB/bh

  // K tile (64 keys): [d-half h][row] 16B slots: addr = h*1024 + row*16
  // V tile (64 keys): [kh][quad][dv] 16B slots: addr = kh*4096 + quad*1024 + dv*16
  __shared__ __align__(16) char Kl[4][2048];
  __shared__ __align__(16) char Vl[4][8192];

  const int q0 = qb * 64 + w * 16;
  // Q x32 B-frag: lane(quad,l15): k=quad*8+j -> d (quads 0,1 real, quads 2,3 zero)
  bf16x8 qB8;
  {
    bf16x8 qv = *(const bf16x8*)(Qp + (long)(q0 + l15) * 16 + (quad & 1) * 8);
    bf16x8 zq = {};
    qB8 = (quad < 2) ? qv : zq;
  }

  f32x4 O[4] = {};           // O^T frags: lane holds (q=l15, dv=dt*16+quad*4+r)
  f32x4 lpacc = {};          // ones-MFMA: every row = sum_k P[k][q=l15]
  const f32x4 zf = {0.f, 0.f, 0.f, 0.f};

  bf16x8 ones8;
#pragma unroll
  for (int i = 0; i < 8; i++) ones8[i] = (bf16_t)1.f;

  // staging sources
  const char* vsrc = Vg + (long)lane * 16;                // + t*8192 + chunk*1024
  const char* ksrc = Kg + (long)lane * 32 + (w - 2) * 16; // w>=2 only: K half (w-2)

  auto stage = [&](int t, int buf) {
    if (w < 2) {
#pragma unroll
      for (int c = 0; c < 2; c++)
        GLOAD_LDS16(vsrc + (long)t * 8192 + (w * 2 + c) * 1024, &Vl[buf][(w * 2 + c) * 1024]);
    } else {
#pragma unroll
      for (int c = 0; c < 2; c++)
        GLOAD_LDS16(vsrc + (long)t * 8192 + ((w - 2) * 2 + 4 + c) * 1024,
                    &Vl[buf][((w - 2) * 2 + 4 + c) * 1024]);
      GLOAD_LDS16(ksrc + (long)t * 2048, &Kl[buf][(w - 2) * 1024]);
    }
  };

  const int krow_off = (quad & 1) * 1024;   // quads 0,2 -> d-half 0; 1,3 -> half 1

  auto compute = [&](int buf) {
#pragma unroll
    for (int kh = 0; kh < 2; kh++) {
      bf16x8 k0 = *(const bf16x8*)(&Kl[buf][krow_off + (kh * 32 + l15) * 16]);
      bf16x8 k1 = *(const bf16x8*)(&Kl[buf][krow_off + (kh * 32 + 16 + l15) * 16]);
      f32x4 S0 = __builtin_amdgcn_mfma_f32_16x16x32_bf16(k0, qB8, zf, 0, 0, 0);
      f32x4 S1 = __builtin_amdgcn_mfma_f32_16x16x32_bf16(k1, qB8, zf, 0, 0, 0);
      bf16x8 pb;
      pb[0] = (bf16_t)__builtin_amdgcn_exp2f(S0[0]);
      pb[1] = (bf16_t)__builtin_amdgcn_exp2f(S0[1]);
      pb[2] = (bf16_t)__builtin_amdgcn_exp2f(S0[2]);
      pb[3] = (bf16_t)__builtin_amdgcn_exp2f(S0[3]);
      pb[4] = (bf16_t)__builtin_amdgcn_exp2f(S1[0]);
      pb[5] = (bf16_t)__builtin_amdgcn_exp2f(S1[1]);
      pb[6] = (bf16_t)__builtin_amdgcn_exp2f(S1[2]);
      pb[7] = (bf16_t)__builtin_amdgcn_exp2f(S1[3]);
      lpacc = __builtin_amdgcn_mfma_f32_16x16x32_bf16(ones8, pb, lpacc, 0, 0, 0);
#pragma unroll
      for (int dt = 0; dt < 4; dt++) {
        bf16x8 vA = *(const bf16x8*)(&Vl[buf][kh * 4096 + quad * 1024 + (dt * 16 + l15) * 16]);
        O[dt] = __builtin_amdgcn_mfma_f32_16x16x32_bf16(vA, pb, O[dt], 0, 0, 0);
      }
    }
  };

  stage(0, 0);
  stage(1, 1);
#pragma unroll 4
  for (int t = 0; t < 64; t++) {
    if (t < 63) {
      if (w < 2) asm volatile("s_waitcnt vmcnt(2)" ::: "memory");
      else       asm volatile("s_waitcnt vmcnt(3)" ::: "memory");
    } else {
      asm volatile("s_waitcnt vmcnt(0)" ::: "memory");
    }
    __builtin_amdgcn_s_barrier();        // all waves' tile-t loads retired -> tile t complete
    __builtin_amdgcn_sched_barrier(0);   // pin: no ds_read hoisted above the barrier
    if (t + 2 < 64) stage(t + 2, (t + 2) & 3);
    compute(t & 3);
  }

  // lpacc rows all equal the key-sum for q=l15
  float rl = __builtin_amdgcn_rcpf(lpacc[0]);
  int q = q0 + l15;
  long colq = q & 511;
  long rowbase = (long)b * 1024 + (long)h * 128 + (q >> 9);
#pragma unroll
  for (int dt = 0; dt < 4; dt++) {
#pragma unroll
    for (int r = 0; r < 4; r++) {
      int dv = dt * 16 + quad * 4 + r;
      float val = O[dt][r] * rl;
      float hs = val * fminf(fmaxf(val + 3.f, 0.f), 6.f) * (1.f / 6.f);
      outp[(rowbase + (long)dv * 2) * 512 + colq] = (bf16_t)hs;
    }
  }
}

extern "C" void kernel_launch(void* const* d_in, const int* in_sizes, int n_in,
                              void* d_out, int out_size, void* d_ws, size_t ws_size,
                              hipStream_t stream)
{
  const float* x    = (const float*)d_in[0];
  const float* Wkv  = (const float*)d_in[1];
  const float* bkv  = (const float*)d_in[2];
  const float* g_kv = (const float*)d_in[3];
  const float* b_kv = (const float*)d_in[4];
  const float* m_kv = (const float*)d_in[5];
  const float* v_kv = (const float*)d_in[6];
  const float* Wq   = (const float*)d_in[7];
  const float* bq   = (const float*)d_in[8];
  const float* g_q  = (const float*)d_in[9];
  const float* b_q  = (const float*)d_in[10];
  const float* m_q  = (const float*)d_in[11];
  const float* v_q  = (const float*)d_in[12];
  const float* Wp   = (const float*)d_in[13];
  const float* bp   = (const float*)d_in[14];
  const float* g_p  = (const float*)d_in[15];
  const float* b_p  = (const float*)d_in[16];
  const float* m_p  = (const float*)d_in[17];
  const float* v_p  = (const float*)d_in[18];

  char* ws = (char*)d_ws;
  bf16_t* xb   = (bf16_t*)ws; ws += (long)8 * 4096 * 256 * 2;
  bf16_t* WkT  = (bf16_t*)ws; ws += (long)128 * 256 * 2;
  bf16_t* WvT  = (bf16_t*)ws; ws += (long)512 * 256 * 2;
  bf16_t* Wq_t = (bf16_t*)ws; ws += (long)128 * 256 * 2;
  bf16_t* Wp_t = (bf16_t*)ws; ws += (long)512 * 512 * 2;
  bf16_t* Qbuf = (bf16_t*)ws; ws += (long)64 * 1024 * 16 * 2;
  bf16_t* Kbuf = (bf16_t*)ws; ws += (long)64 * 4096 * 16 * 2;
  bf16_t* Vtb  = (bf16_t*)ws; ws += (long)64 * 64 * 4096 * 2;
  bf16_t* outp = (bf16_t*)ws; ws += (long)8192 * 512 * 2;
  ws += 16384;  // slack

  cvt_f32_bf16<<<dim3(4096), 256, 0, stream>>>(x, xb, (long)8 * 4096 * 256);

  wkv_split_transpose<<<dim3(20, 8), dim3(32, 8), 0, stream>>>(Wkv, WkT, WvT);
  transpose_f32_bf16<<<dim3(4, 8),   dim3(32, 8), 0, stream>>>(Wq, Wq_t, 256, 128);
  transpose_f32_bf16<<<dim3(16, 16), dim3(32, 8), 0, stream>>>(Wp, Wp_t, 512, 512);

  gemm_bn<0><<<dim3(512, 2), 256, 0, stream>>>(xb, WkT, bkv, g_kv, b_kv, m_kv, v_kv, Kbuf, nullptr);
  gemm_bn<3><<<dim3(8, 512), 256, 0, stream>>>(WvT, xb, bkv, g_kv, b_kv, m_kv, v_kv, Vtb, nullptr);
  gemm_bn<1><<<dim3(128, 2), 256, 0, stream>>>(xb, Wq_t, bq, g_q, b_q, m_q, v_q, Qbuf, nullptr);

  attn_kernel<<<dim3(1024), 256, 0, stream>>>(Qbuf, Kbuf, Vtb, outp);

  gemm_bn<2><<<dim3(128, 8), 256, 0, stream>>>(outp, Wp_t, bp, g_p, b_p, m_p, v_p, nullptr, (float*)d_out);
}